// Round 14
// baseline (152.176 us; speedup 1.0000x reference)
//
#include <hip/hip_runtime.h>

typedef unsigned short u16;
typedef unsigned int u32;
typedef __attribute__((ext_vector_type(4))) float f32x4;
typedef __attribute__((ext_vector_type(8))) short short8;

#define HWD 56
#define HW2 3136
#define C_IN 128
#define K_OUT 256
#define N_IMG 32
#define CHW_IN 401408
#define CHW_OUT 802816
#define PIX 100352
#define WQ_N 294912
// xt3: [cq4][gRow 1872][58][c32] bf16. Image n = gRows n*58 .. n*58+57 (rows n*58, n*58+57 zero).
#define GROWS 1872
#define XROW 1856
#define XPLANE (GROWS * XROW)
#define NSLICE 1568            // 784 nt * 2 wn
#define CV_OFF 33554432u
#define WS_NEED_BF16 (CV_OFF + (size_t)PIX * K_OUT * 2)

__device__ __forceinline__ u16 f2bf(float f) {
    u32 u = __float_as_uint(f);
    u32 r = u + 0x7FFFu + ((u >> 16) & 1u);
    return (u16)(r >> 16);
}

__device__ __forceinline__ void glds16(const u16* g, u16* l) {
    __builtin_amdgcn_global_load_lds(
        (const __attribute__((address_space(1))) void*)g,
        (__attribute__((address_space(3))) void*)l, 16, 0, 0);
}

__global__ void maxabs_k(const float* __restrict__ w, u32* __restrict__ wsmax) {
    float m = 0.f;
    for (int i = blockIdx.x * blockDim.x + threadIdx.x; i < WQ_N; i += gridDim.x * blockDim.x)
        m = fmaxf(m, fabsf(w[i]));
    for (int off = 32; off; off >>= 1)
        m = fmaxf(m, __shfl_xor(m, off));
    __shared__ float sm[4];
    int lane = threadIdx.x & 63, wid = threadIdx.x >> 6;
    if (lane == 0) sm[wid] = m;
    __syncthreads();
    if (threadIdx.x == 0) {
        float mm = fmaxf(fmaxf(sm[0], sm[1]), fmaxf(sm[2], sm[3]));
        atomicMax(wsmax, __float_as_uint(mm));
    }
}

// wqt: [kt36][mt2][oct4][m128][8]; kt = cq*9 + tap; c = cq*32 + oct*8 + j; m = mt*128 + mrow
__global__ void quant_t_k5(const float* __restrict__ w, const u32* __restrict__ wsmax,
                           u16* __restrict__ wqt) {
    int o = blockIdx.x * 256 + threadIdx.x;
    if (o >= WQ_N) return;
    int j = o & 7;
    int mrow = (o >> 3) & 127;
    int oct = (o >> 10) & 3;
    int mt = (o >> 12) & 1;
    int kt = o >> 13;
    int cq = kt / 9, tap = kt - cq * 9;
    int c = cq * 32 + oct * 8 + j;
    int m = mt * 128 + mrow;
    float scale = __uint_as_float(wsmax[0]) / 7.0f;
    float q = rintf(w[(m * 128 + c) * 9 + tap] / scale);
    q = fminf(fmaxf(q, -7.0f), 7.0f);
    wqt[o] = f2bf(q * scale);
}

// zero halos of xt3: full rows {n*58, n*58+57, 1856..1871} + data-row cols {0,57}
__global__ void halo_zero(u16* __restrict__ xt3) {
    int i = blockIdx.x * 256 + threadIdx.x;   // 131,584 total
    u32 addr;
    if (i < 74240) {
        int rowIdx = i / 928, rem = i - rowIdx * 928;
        int cq = rem / 232, c = rem - cq * 232;
        int row = rowIdx < 64 ? (rowIdx >> 1) * 58 + (rowIdx & 1) * 57 : 1856 + (rowIdx - 64);
        addr = (u32)cq * XPLANE + row * XROW + c * 8;
    } else {
        int j = i - 74240;
        int rowd = j >> 5, rem = j & 31;
        int side = rem >> 4, cq = (rem >> 2) & 3, o4 = rem & 3;
        int n = rowd / 56, h = rowd - n * 56;
        int row = n * 58 + 1 + h, col = side * 57;
        addr = (u32)cq * XPLANE + (row * 58 + col) * 32 + o4 * 8;
    }
    *(uint4*)(xt3 + addr) = (uint4){0, 0, 0, 0};
}

// x (NCHW f32) -> xt3 interior
__global__ __launch_bounds__(256) void pad_transpose(const float* __restrict__ x,
                                                     u16* __restrict__ xt3) {
    __shared__ float T[128][57];
    const int tid = threadIdx.x;
    const int n = blockIdx.x / HWD;
    const int h = blockIdx.x - n * HWD;
    const float* srow = x + (size_t)n * CHW_IN + h * HWD;
    #pragma unroll
    for (int it = 0; it < 7; ++it) {
        int i = tid + it * 256;
        int c = i / 14, q = i - c * 14;
        float4 v = *(const float4*)(srow + c * HW2 + q * 4);
        T[c][q * 4 + 0] = v.x; T[c][q * 4 + 1] = v.y;
        T[c][q * 4 + 2] = v.z; T[c][q * 4 + 3] = v.w;
    }
    __syncthreads();
    const int gRow = n * 58 + 1 + h;
    #pragma unroll
    for (int it = 0; it < 4; ++it) {
        int i = tid + it * 256;
        if (i < 56 * 16) {
            int w = i >> 4, oc = i & 15;
            int cq = oc >> 2, o4 = oc & 3;
            union { u16 us[8]; uint4 v4; } pk;
            #pragma unroll
            for (int j = 0; j < 8; ++j) pk.us[j] = f2bf(T[oc * 8 + j][w]);
            *(uint4*)(xt3 + (size_t)cq * XPLANE + (gRow * 58 + (w + 1)) * 32 + o4 * 8) = pk.v4;
        }
    }
}

// ===== R13 conv (dense-B glds, 3-buf counted-vmcnt) + inner mt-loop: grid 784, ~1.02 rounds =====
// Block: nt (128 px), two passes mt=0,1 (128 ch each). 4 waves (2wm x 2wn, 64x64).
template <bool BF16OUT>
__global__ __launch_bounds__(256, 3) void conv_m(const u16* __restrict__ xt3,
                                                 const u16* __restrict__ wqt,
                                                 float* __restrict__ out,
                                                 u16* __restrict__ cvout,
                                                 float* __restrict__ P) {
    __shared__ __align__(16) u16 lds[3][2][4096];   // 48 KB
    const int tid = threadIdx.x;
    const int lane = tid & 63;
    const int w4 = tid >> 6;           // 4 waves, 2m x 2n
    const int wm = w4 >> 1, wn = w4 & 1;
    const int fr = lane & 15, fq = lane >> 4;
    // XCD swizzle: 784 = 8*98 bijective
    const int nt = (blockIdx.x & 7) * 98 + (blockIdx.x >> 3);
    const int pixbase = nt * 128;

    // dense-B per-lane sites: instr j covers px group pg = w4*2+j (16 px), this lane's
    // px = pg*16 + (lane&15), oct = lane>>4. Site = elem offset in cq plane at tap (0,0).
    u32 siteJ[2];
    #pragma unroll
    for (int j = 0; j < 2; ++j) {
        int px = pixbase + (w4 * 2 + j) * 16 + (lane & 15);
        int img = px / HW2, hw = px - img * HW2;
        int g = img * 58 + 1 + hw / HWD;
        int wc = hw % HWD + 1;
        siteJ[j] = (u32)(((g - 1) * 58 + (wc - 1)) * 32 + (lane >> 4) * 8);
    }

#define STAGE(buf, kt_, mt_) do {                                                \
        const int cq_ = (kt_) / 9, tap_ = (kt_) % 9;                             \
        const int r_ = tap_ / 3, s_ = tap_ - r_ * 3;                             \
        const u16* ga_ = wqt + (size_t)((kt_) * 2 + (mt_)) * 4096 + (w4 * 2) * 512 + lane * 8; \
        glds16(ga_,       &lds[buf][0][(w4 * 2 + 0) * 512]);                     \
        glds16(ga_ + 512, &lds[buf][0][(w4 * 2 + 1) * 512]);                     \
        const u16* gb_ = xt3 + (size_t)cq_ * XPLANE + (r_ * 58 + s_) * 32;       \
        glds16(gb_ + siteJ[0], &lds[buf][1][(w4 * 2 + 0) * 512]);                \
        glds16(gb_ + siteJ[1], &lds[buf][1][(w4 * 2 + 1) * 512]);                \
    } while (0)
#define PHASE_BODY(buf) do {                                                     \
        short8 af[4], bf[4];                                                     \
        _Pragma("unroll") for (int mi = 0; mi < 4; ++mi)                         \
            af[mi] = *(const short8*)&lds[buf][0][fq * 1024 + (wm * 64 + mi * 16 + fr) * 8]; \
        _Pragma("unroll") for (int ni = 0; ni < 4; ++ni)                         \
            bf[ni] = *(const short8*)&lds[buf][1][(wn * 4 + ni) * 512 + fq * 128 + fr * 8]; \
        asm volatile("s_waitcnt lgkmcnt(0)" ::: "memory");                       \
        __builtin_amdgcn_sched_barrier(0);                                       \
        __builtin_amdgcn_s_setprio(1);                                           \
        _Pragma("unroll") for (int mi = 0; mi < 4; ++mi)                         \
            _Pragma("unroll") for (int ni = 0; ni < 4; ++ni)                     \
                acc[mi][ni] = __builtin_amdgcn_mfma_f32_16x16x32_bf16(           \
                    af[mi], bf[ni], acc[mi][ni], 0, 0, 0);                       \
        __builtin_amdgcn_s_setprio(0);                                           \
    } while (0)
#define BAR() __builtin_amdgcn_s_barrier()
#define GATE4() asm volatile("s_waitcnt vmcnt(4)" ::: "memory")
#define GATE0() asm volatile("s_waitcnt vmcnt(0)" ::: "memory")

    f32x4 acc[4][4];

    #pragma unroll 1
    for (int mt = 0; mt < 2; ++mt) {
        #pragma unroll
        for (int a = 0; a < 4; ++a)
            #pragma unroll
            for (int b = 0; b < 4; ++b)
                acc[a][b] = (f32x4){0.f, 0.f, 0.f, 0.f};

        // prologue: kt0 -> buf0, kt1 -> buf1; keep kt1's 4 in flight
        STAGE(0, 0, mt);
        STAGE(1, 1, mt);
        GATE4();
        BAR();

        #pragma unroll 1
        for (int tt = 0; tt < 12; ++tt) {
            #pragma unroll
            for (int u = 0; u < 3; ++u) {
                const int t = tt * 3 + u;
                const int bs = (u + 2) % 3;
                if (t < 34) STAGE(bs, t + 2, mt);
                PHASE_BODY(u);
                if (t < 34) GATE4();
                else if (t == 34) GATE0();
                BAR();
            }
        }

        // ---- fused per-channel partials (D: col=lane&15 -> pixel, row -> channel) ----
        const int slice = nt * 2 + wn;
        #pragma unroll
        for (int mi = 0; mi < 4; ++mi)
            #pragma unroll
            for (int j = 0; j < 4; ++j) {
                float s = 0.f, q = 0.f;
                #pragma unroll
                for (int ni = 0; ni < 4; ++ni) {
                    float v = acc[mi][ni][j];
                    s += v; q += v * v;
                }
                #pragma unroll
                for (int msk = 1; msk < 16; msk <<= 1) {
                    s += __shfl_xor(s, msk);
                    q += __shfl_xor(q, msk);
                }
                if (fr == 0) {
                    int ch = mt * 128 + wm * 64 + mi * 16 + fq * 4 + j;
                    float* dst = P + ((size_t)ch * NSLICE + slice) * 2;
                    dst[0] = s; dst[1] = q;
                }
            }

        if (BF16OUT) {
            // dense epilogue: LDS transpose to T[ch128][px 136pad], 16B stores
            u16* T = (u16*)&lds[0][0][0];        // 34,816 B (spans bufs 0,1 + part of 2)
            #pragma unroll
            for (int mi = 0; mi < 4; ++mi)
                #pragma unroll
                for (int ni = 0; ni < 4; ++ni) {
                    int px_l = wn * 64 + ni * 16 + fr;
                    int ch_l = wm * 64 + mi * 16 + fq * 4;
                    #pragma unroll
                    for (int j = 0; j < 4; ++j)
                        T[(ch_l + j) * 136 + px_l] = f2bf(acc[mi][ni][j]);
                }
            __syncthreads();
            #pragma unroll
            for (int it = 0; it < 8; ++it) {
                int q = tid + it * 256;
                int ch_l = q >> 4, pg = q & 15;
                uint4 v = *(const uint4*)&T[ch_l * 136 + pg * 8];
                *(uint4*)&cvout[(size_t)(mt * 128 + ch_l) * PIX + pixbase + pg * 8] = v;
            }
            __syncthreads();   // T reads done before next pass's STAGE overwrites lds
        } else {
            #pragma unroll
            for (int ni = 0; ni < 4; ++ni) {
                int pix = pixbase + wn * 64 + ni * 16 + fr;
                int n = pix / HW2;
                int hw = pix - n * HW2;
                size_t obase = (size_t)n * CHW_OUT + hw;
                #pragma unroll
                for (int mi = 0; mi < 4; ++mi) {
                    int ch = mt * 128 + wm * 64 + mi * 16 + fq * 4;
                    #pragma unroll
                    for (int j = 0; j < 4; ++j)
                        out[obase + (size_t)(ch + j) * HW2] = acc[mi][ni][j];
                }
            }
            __syncthreads();
        }
    }
#undef STAGE
#undef PHASE_BODY
#undef BAR
#undef GATE4
#undef GATE0
}

__global__ void stats_fin(const float* __restrict__ P, const float* __restrict__ gamma,
                          const float* __restrict__ beta, float* __restrict__ stats) {
    int ch = blockIdx.x;
    int tid = threadIdx.x;
    float s = 0.f, q = 0.f;
    const float* base = P + (size_t)ch * NSLICE * 2;
    for (int i = tid; i < NSLICE; i += 256) {
        float2 v = *(const float2*)(base + i * 2);
        s += v.x; q += v.y;
    }
    for (int m = 32; m; m >>= 1) { s += __shfl_xor(s, m); q += __shfl_xor(q, m); }
    __shared__ float ss[4], qs[4];
    int l = tid & 63, w = tid >> 6;
    if (l == 0) { ss[w] = s; qs[w] = q; }
    __syncthreads();
    if (tid == 0) {
        float S = ss[0] + ss[1] + ss[2] + ss[3];
        float Q = qs[0] + qs[1] + qs[2] + qs[3];
        float mean = S / (float)PIX;
        float var = Q / (float)PIX - mean * mean;
        float inv = gamma[ch] * rsqrtf(var + 1e-5f);
        stats[2 * ch] = inv;
        stats[2 * ch + 1] = beta[ch] - mean * inv;
    }
}

// cvout [ch][global-pix] bf16 -> out NCHW f32
__global__ void bn_relu_nchw(const u16* __restrict__ cvout, float* __restrict__ out,
                             const float* __restrict__ stats) {
    const int b = blockIdx.x;            // 256 ch * 49 groups
    const int ch = b / 49, g = b - ch * 49;
    const float inv = stats[2 * ch], sh = stats[2 * ch + 1];
    const int p8 = (g * 256 + threadIdx.x) * 8;
    short8 v = *(const short8*)&cvout[(size_t)ch * PIX + p8];
    const int n = p8 / HW2;
    const int hw = p8 - n * HW2;
    float* dst = out + ((size_t)n * K_OUT + ch) * HW2 + hw;
    f32x4 o0, o1;
    #pragma unroll
    for (int j = 0; j < 4; ++j) {
        float a = __uint_as_float(((u32)(u16)v[j]) << 16);
        float bb = __uint_as_float(((u32)(u16)v[j + 4]) << 16);
        o0[j] = fmaxf(a * inv + sh, 0.f);
        o1[j] = fmaxf(bb * inv + sh, 0.f);
    }
    *(f32x4*)dst = o0;
    *(f32x4*)(dst + 4) = o1;
}

__global__ void bn_relu_f32(float* __restrict__ out, const float* __restrict__ stats) {
    const int n4 = ((size_t)N_IMG * K_OUT * HW2) / 4;
    int stride = gridDim.x * blockDim.x;
    for (int i = blockIdx.x * blockDim.x + threadIdx.x; i < n4; i += stride) {
        int ch = (i / (HW2 / 4)) & (K_OUT - 1);
        float inv = stats[2 * ch], sh = stats[2 * ch + 1];
        f32x4 v = ((f32x4*)out)[i];
        #pragma unroll
        for (int j = 0; j < 4; ++j)
            v[j] = fmaxf(v[j] * inv + sh, 0.f);
        ((f32x4*)out)[i] = v;
    }
}

extern "C" void kernel_launch(void* const* d_in, const int* in_sizes, int n_in,
                              void* d_out, int out_size, void* d_ws, size_t ws_size,
                              hipStream_t stream) {
    const float* x = (const float*)d_in[0];
    const float* w = (const float*)d_in[1];
    const float* gamma = (const float*)d_in[2];
    const float* beta = (const float*)d_in[3];
    float* out = (float*)d_out;

    char* ws = (char*)d_ws;
    u32* wsmax = (u32*)ws;                         // [0,64)
    float* stats = (float*)(ws + 64);              // 2KB
    u16* wqt = (u16*)(ws + 4096);                  // 589,824 B
    float* P = (float*)(ws + 1048576u);            // 3,211,264 B
    u16* xt3 = (u16*)(ws + 4325376u);              // 27,795,456 B (ends 32,120,832)
    u16* cvout = (u16*)(ws + CV_OFF);              // 51,380,224 B
    const bool bf16path = (ws_size >= WS_NEED_BF16);

    hipMemsetAsync(wsmax, 0, 64, stream);
    maxabs_k<<<128, 256, 0, stream>>>(w, wsmax);
    quant_t_k5<<<WQ_N / 256, 256, 0, stream>>>(w, wsmax, wqt);
    halo_zero<<<514, 256, 0, stream>>>(xt3);
    pad_transpose<<<N_IMG * HWD, 256, 0, stream>>>(x, xt3);
    if (bf16path) {
        conv_m<true><<<784, 256, 0, stream>>>(xt3, wqt, out, cvout, P);
        stats_fin<<<K_OUT, 256, 0, stream>>>(P, gamma, beta, stats);
        bn_relu_nchw<<<K_OUT * 49, 256, 0, stream>>>(cvout, out, stats);
    } else {
        conv_m<false><<<784, 256, 0, stream>>>(xt3, wqt, out, cvout, P);
        stats_fin<<<K_OUT, 256, 0, stream>>>(P, gamma, beta, stats);
        bn_relu_f32<<<4096, 256, 0, stream>>>(out, stats);
    }
}

// Round 15
// 131.197 us; speedup vs baseline: 1.1599x; 1.1599x over previous
//
#include <hip/hip_runtime.h>

typedef unsigned short u16;
typedef unsigned int u32;
typedef __attribute__((ext_vector_type(4))) float f32x4;
typedef __attribute__((ext_vector_type(8))) short short8;

#define HWD 56
#define HW2 3136
#define C_IN 128
#define K_OUT 256
#define N_IMG 32
#define CHW_IN 401408
#define CHW_OUT 802816
#define PIX 100352
#define WQ_N 294912
// xt3: [cq4][gRow 1872][58][c32] bf16. Image n = gRows n*58 .. n*58+57 (rows n*58, n*58+57 zero).
#define GROWS 1872
#define XROW 1856
#define XPLANE (GROWS * XROW)
#define NSLICE 1568            // 784 nt * 2 wn
#define CV_OFF 33554432u
#define WS_NEED_BF16 (CV_OFF + (size_t)PIX * K_OUT * 2)

__device__ __forceinline__ u16 f2bf(float f) {
    u32 u = __float_as_uint(f);
    u32 r = u + 0x7FFFu + ((u >> 16) & 1u);
    return (u16)(r >> 16);
}

__device__ __forceinline__ void glds16(const u16* g, u16* l) {
    __builtin_amdgcn_global_load_lds(
        (const __attribute__((address_space(1))) void*)g,
        (__attribute__((address_space(3))) void*)l, 16, 0, 0);
}

__global__ void maxabs_k(const float* __restrict__ w, u32* __restrict__ wsmax) {
    float m = 0.f;
    for (int i = blockIdx.x * blockDim.x + threadIdx.x; i < WQ_N; i += gridDim.x * blockDim.x)
        m = fmaxf(m, fabsf(w[i]));
    for (int off = 32; off; off >>= 1)
        m = fmaxf(m, __shfl_xor(m, off));
    __shared__ float sm[4];
    int lane = threadIdx.x & 63, wid = threadIdx.x >> 6;
    if (lane == 0) sm[wid] = m;
    __syncthreads();
    if (threadIdx.x == 0) {
        float mm = fmaxf(fmaxf(sm[0], sm[1]), fmaxf(sm[2], sm[3]));
        atomicMax(wsmax, __float_as_uint(mm));
    }
}

// wqt: [kt36][mt2][oct4][m128][8]; kt = cq*9 + tap; c = cq*32 + oct*8 + j; m = mt*128 + mrow
__global__ void quant_t_k5(const float* __restrict__ w, const u32* __restrict__ wsmax,
                           u16* __restrict__ wqt) {
    int o = blockIdx.x * 256 + threadIdx.x;
    if (o >= WQ_N) return;
    int j = o & 7;
    int mrow = (o >> 3) & 127;
    int oct = (o >> 10) & 3;
    int mt = (o >> 12) & 1;
    int kt = o >> 13;
    int cq = kt / 9, tap = kt - cq * 9;
    int c = cq * 32 + oct * 8 + j;
    int m = mt * 128 + mrow;
    float scale = __uint_as_float(wsmax[0]) / 7.0f;
    float q = rintf(w[(m * 128 + c) * 9 + tap] / scale);
    q = fminf(fmaxf(q, -7.0f), 7.0f);
    wqt[o] = f2bf(q * scale);
}

// zero halos of xt3: full rows {n*58, n*58+57, 1856..1871} + data-row cols {0,57}
__global__ void halo_zero(u16* __restrict__ xt3) {
    int i = blockIdx.x * 256 + threadIdx.x;   // 131,584 total
    u32 addr;
    if (i < 74240) {
        int rowIdx = i / 928, rem = i - rowIdx * 928;
        int cq = rem / 232, c = rem - cq * 232;
        int row = rowIdx < 64 ? (rowIdx >> 1) * 58 + (rowIdx & 1) * 57 : 1856 + (rowIdx - 64);
        addr = (u32)cq * XPLANE + row * XROW + c * 8;
    } else {
        int j = i - 74240;
        int rowd = j >> 5, rem = j & 31;
        int side = rem >> 4, cq = (rem >> 2) & 3, o4 = rem & 3;
        int n = rowd / 56, h = rowd - n * 56;
        int row = n * 58 + 1 + h, col = side * 57;
        addr = (u32)cq * XPLANE + (row * 58 + col) * 32 + o4 * 8;
    }
    *(uint4*)(xt3 + addr) = (uint4){0, 0, 0, 0};
}

// x (NCHW f32) -> xt3 interior
__global__ __launch_bounds__(256) void pad_transpose(const float* __restrict__ x,
                                                     u16* __restrict__ xt3) {
    __shared__ float T[128][57];
    const int tid = threadIdx.x;
    const int n = blockIdx.x / HWD;
    const int h = blockIdx.x - n * HWD;
    const float* srow = x + (size_t)n * CHW_IN + h * HWD;
    #pragma unroll
    for (int it = 0; it < 7; ++it) {
        int i = tid + it * 256;
        int c = i / 14, q = i - c * 14;
        float4 v = *(const float4*)(srow + c * HW2 + q * 4);
        T[c][q * 4 + 0] = v.x; T[c][q * 4 + 1] = v.y;
        T[c][q * 4 + 2] = v.z; T[c][q * 4 + 3] = v.w;
    }
    __syncthreads();
    const int gRow = n * 58 + 1 + h;
    #pragma unroll
    for (int it = 0; it < 4; ++it) {
        int i = tid + it * 256;
        if (i < 56 * 16) {
            int w = i >> 4, oc = i & 15;
            int cq = oc >> 2, o4 = oc & 3;
            union { u16 us[8]; uint4 v4; } pk;
            #pragma unroll
            for (int j = 0; j < 8; ++j) pk.us[j] = f2bf(T[oc * 8 + j][w]);
            *(uint4*)(xt3 + (size_t)cq * XPLANE + (gRow * 58 + (w + 1)) * 32 + o4 * 8) = pk.v4;
        }
    }
}

// ===== R13 (best measured): dense-B glds (pre-swizzled per-lane global, linear LDS dest) =====
// Block 128ch(mt) x 128px, 4 waves (2wm x 2wn, 64x64 each). 3-buf BK=32 counted-vmcnt.
// Grid 1568: mt-pairs adjacent on same XCD run CONCURRENTLY and share B in L2 (load-bearing;
// R14's serial mt-loop doubled FETCH). B glds: lane -> (oct=lane>>4, px=lane&15): 1 KB span.
// LDS B layout [pg8][oct4][px16][8]: frag read 256B-contiguous per quarter-wave, conflict-free.
template <bool BF16OUT>
__global__ __launch_bounds__(256, 3) void conv_m(const u16* __restrict__ xt3,
                                                 const u16* __restrict__ wqt,
                                                 float* __restrict__ out,
                                                 u16* __restrict__ cvout,
                                                 float* __restrict__ P) {
    __shared__ __align__(16) u16 lds[3][2][4096];   // 48 KB
    const int tid = threadIdx.x;
    const int lane = tid & 63;
    const int w4 = tid >> 6;           // 4 waves, 2m x 2n
    const int wm = w4 >> 1, wn = w4 & 1;
    const int fr = lane & 15, fq = lane >> 4;
    // XCD swizzle: 1568 = 8*196 bijective; mt-pairs (same nt) adjacent on same XCD
    const int swz = (blockIdx.x & 7) * 196 + (blockIdx.x >> 3);
    const int nt = swz >> 1, mt = swz & 1;
    const int pixbase = nt * 128;

    // dense-B per-lane sites: instr j covers px group pg = w4*2+j (16 px), this lane's
    // px = pg*16 + (lane&15), oct = lane>>4. Site = elem offset in cq plane at tap (0,0).
    u32 siteJ[2];
    #pragma unroll
    for (int j = 0; j < 2; ++j) {
        int px = pixbase + (w4 * 2 + j) * 16 + (lane & 15);
        int img = px / HW2, hw = px - img * HW2;
        int g = img * 58 + 1 + hw / HWD;
        int wc = hw % HWD + 1;
        siteJ[j] = (u32)(((g - 1) * 58 + (wc - 1)) * 32 + (lane >> 4) * 8);
    }

#define STAGE(buf, kt_) do {                                                     \
        const int cq_ = (kt_) / 9, tap_ = (kt_) % 9;                             \
        const int r_ = tap_ / 3, s_ = tap_ - r_ * 3;                             \
        const u16* ga_ = wqt + (size_t)((kt_) * 2 + mt) * 4096 + (w4 * 2) * 512 + lane * 8; \
        glds16(ga_,       &lds[buf][0][(w4 * 2 + 0) * 512]);                     \
        glds16(ga_ + 512, &lds[buf][0][(w4 * 2 + 1) * 512]);                     \
        const u16* gb_ = xt3 + (size_t)cq_ * XPLANE + (r_ * 58 + s_) * 32;       \
        glds16(gb_ + siteJ[0], &lds[buf][1][(w4 * 2 + 0) * 512]);                \
        glds16(gb_ + siteJ[1], &lds[buf][1][(w4 * 2 + 1) * 512]);                \
    } while (0)
#define PHASE_BODY(buf) do {                                                     \
        short8 af[4], bf[4];                                                     \
        _Pragma("unroll") for (int mi = 0; mi < 4; ++mi)                         \
            af[mi] = *(const short8*)&lds[buf][0][fq * 1024 + (wm * 64 + mi * 16 + fr) * 8]; \
        _Pragma("unroll") for (int ni = 0; ni < 4; ++ni)                         \
            bf[ni] = *(const short8*)&lds[buf][1][(wn * 4 + ni) * 512 + fq * 128 + fr * 8]; \
        asm volatile("s_waitcnt lgkmcnt(0)" ::: "memory");                       \
        __builtin_amdgcn_sched_barrier(0);                                       \
        __builtin_amdgcn_s_setprio(1);                                           \
        _Pragma("unroll") for (int mi = 0; mi < 4; ++mi)                         \
            _Pragma("unroll") for (int ni = 0; ni < 4; ++ni)                     \
                acc[mi][ni] = __builtin_amdgcn_mfma_f32_16x16x32_bf16(           \
                    af[mi], bf[ni], acc[mi][ni], 0, 0, 0);                       \
        __builtin_amdgcn_s_setprio(0);                                           \
    } while (0)
#define BAR() __builtin_amdgcn_s_barrier()
#define GATE4() asm volatile("s_waitcnt vmcnt(4)" ::: "memory")
#define GATE0() asm volatile("s_waitcnt vmcnt(0)" ::: "memory")

    f32x4 acc[4][4];
    #pragma unroll
    for (int a = 0; a < 4; ++a)
        #pragma unroll
        for (int b = 0; b < 4; ++b)
            acc[a][b] = (f32x4){0.f, 0.f, 0.f, 0.f};

    // prologue: kt0 -> buf0, kt1 -> buf1; keep kt1's 4 in flight
    STAGE(0, 0);
    STAGE(1, 1);
    GATE4();
    BAR();

    #pragma unroll 1
    for (int tt = 0; tt < 12; ++tt) {
        #pragma unroll
        for (int u = 0; u < 3; ++u) {
            const int t = tt * 3 + u;
            const int bs = (u + 2) % 3;
            if (t < 34) STAGE(bs, t + 2);
            PHASE_BODY(u);
            if (t < 34) GATE4();
            else if (t == 34) GATE0();
            BAR();
        }
    }
#undef STAGE
#undef PHASE_BODY

    // ---- fused per-channel partials (D: col=lane&15 -> pixel, row -> channel) ----
    const int slice = nt * 2 + wn;
    #pragma unroll
    for (int mi = 0; mi < 4; ++mi)
        #pragma unroll
        for (int j = 0; j < 4; ++j) {
            float s = 0.f, q = 0.f;
            #pragma unroll
            for (int ni = 0; ni < 4; ++ni) {
                float v = acc[mi][ni][j];
                s += v; q += v * v;
            }
            #pragma unroll
            for (int msk = 1; msk < 16; msk <<= 1) {
                s += __shfl_xor(s, msk);
                q += __shfl_xor(q, msk);
            }
            if (fr == 0) {
                int ch = mt * 128 + wm * 64 + mi * 16 + fq * 4 + j;
                float* dst = P + ((size_t)ch * NSLICE + slice) * 2;
                dst[0] = s; dst[1] = q;
            }
        }

    if (BF16OUT) {
        // dense epilogue: LDS transpose to T[ch128][px 136pad], 16B stores
        u16* T = (u16*)&lds[0][0][0];        // 34,816 B of the 48KB
        #pragma unroll
        for (int mi = 0; mi < 4; ++mi)
            #pragma unroll
            for (int ni = 0; ni < 4; ++ni) {
                int px_l = wn * 64 + ni * 16 + fr;
                int ch_l = wm * 64 + mi * 16 + fq * 4;
                #pragma unroll
                for (int j = 0; j < 4; ++j)
                    T[(ch_l + j) * 136 + px_l] = f2bf(acc[mi][ni][j]);
            }
        __syncthreads();
        #pragma unroll
        for (int it = 0; it < 8; ++it) {
            int q = tid + it * 256;
            int ch_l = q >> 4, pg = q & 15;
            uint4 v = *(const uint4*)&T[ch_l * 136 + pg * 8];
            *(uint4*)&cvout[(size_t)(mt * 128 + ch_l) * PIX + pixbase + pg * 8] = v;
        }
    } else {
        #pragma unroll
        for (int ni = 0; ni < 4; ++ni) {
            int pix = pixbase + wn * 64 + ni * 16 + fr;
            int n = pix / HW2;
            int hw = pix - n * HW2;
            size_t obase = (size_t)n * CHW_OUT + hw;
            #pragma unroll
            for (int mi = 0; mi < 4; ++mi) {
                int ch = mt * 128 + wm * 64 + mi * 16 + fq * 4;
                #pragma unroll
                for (int j = 0; j < 4; ++j)
                    out[obase + (size_t)(ch + j) * HW2] = acc[mi][ni][j];
            }
        }
    }
#undef BAR
#undef GATE4
#undef GATE0
}

__global__ void stats_fin(const float* __restrict__ P, const float* __restrict__ gamma,
                          const float* __restrict__ beta, float* __restrict__ stats) {
    int ch = blockIdx.x;
    int tid = threadIdx.x;
    float s = 0.f, q = 0.f;
    const float* base = P + (size_t)ch * NSLICE * 2;
    for (int i = tid; i < NSLICE; i += 256) {
        float2 v = *(const float2*)(base + i * 2);
        s += v.x; q += v.y;
    }
    for (int m = 32; m; m >>= 1) { s += __shfl_xor(s, m); q += __shfl_xor(q, m); }
    __shared__ float ss[4], qs[4];
    int l = tid & 63, w = tid >> 6;
    if (l == 0) { ss[w] = s; qs[w] = q; }
    __syncthreads();
    if (tid == 0) {
        float S = ss[0] + ss[1] + ss[2] + ss[3];
        float Q = qs[0] + qs[1] + qs[2] + qs[3];
        float mean = S / (float)PIX;
        float var = Q / (float)PIX - mean * mean;
        float inv = gamma[ch] * rsqrtf(var + 1e-5f);
        stats[2 * ch] = inv;
        stats[2 * ch + 1] = beta[ch] - mean * inv;
    }
}

// cvout [ch][global-pix] bf16 -> out NCHW f32
__global__ void bn_relu_nchw(const u16* __restrict__ cvout, float* __restrict__ out,
                             const float* __restrict__ stats) {
    const int b = blockIdx.x;            // 256 ch * 49 groups
    const int ch = b / 49, g = b - ch * 49;
    const float inv = stats[2 * ch], sh = stats[2 * ch + 1];
    const int p8 = (g * 256 + threadIdx.x) * 8;
    short8 v = *(const short8*)&cvout[(size_t)ch * PIX + p8];
    const int n = p8 / HW2;
    const int hw = p8 - n * HW2;
    float* dst = out + ((size_t)n * K_OUT + ch) * HW2 + hw;
    f32x4 o0, o1;
    #pragma unroll
    for (int j = 0; j < 4; ++j) {
        float a = __uint_as_float(((u32)(u16)v[j]) << 16);
        float bb = __uint_as_float(((u32)(u16)v[j + 4]) << 16);
        o0[j] = fmaxf(a * inv + sh, 0.f);
        o1[j] = fmaxf(bb * inv + sh, 0.f);
    }
    *(f32x4*)dst = o0;
    *(f32x4*)(dst + 4) = o1;
}

__global__ void bn_relu_f32(float* __restrict__ out, const float* __restrict__ stats) {
    const int n4 = ((size_t)N_IMG * K_OUT * HW2) / 4;
    int stride = gridDim.x * blockDim.x;
    for (int i = blockIdx.x * blockDim.x + threadIdx.x; i < n4; i += stride) {
        int ch = (i / (HW2 / 4)) & (K_OUT - 1);
        float inv = stats[2 * ch], sh = stats[2 * ch + 1];
        f32x4 v = ((f32x4*)out)[i];
        #pragma unroll
        for (int j = 0; j < 4; ++j)
            v[j] = fmaxf(v[j] * inv + sh, 0.f);
        ((f32x4*)out)[i] = v;
    }
}

extern "C" void kernel_launch(void* const* d_in, const int* in_sizes, int n_in,
                              void* d_out, int out_size, void* d_ws, size_t ws_size,
                              hipStream_t stream) {
    const float* x = (const float*)d_in[0];
    const float* w = (const float*)d_in[1];
    const float* gamma = (const float*)d_in[2];
    const float* beta = (const float*)d_in[3];
    float* out = (float*)d_out;

    char* ws = (char*)d_ws;
    u32* wsmax = (u32*)ws;                         // [0,64)
    float* stats = (float*)(ws + 64);              // 2KB
    u16* wqt = (u16*)(ws + 4096);                  // 589,824 B
    float* P = (float*)(ws + 1048576u);            // 3,211,264 B
    u16* xt3 = (u16*)(ws + 4325376u);              // 27,795,456 B (ends 32,120,832)
    u16* cvout = (u16*)(ws + CV_OFF);              // 51,380,224 B
    const bool bf16path = (ws_size >= WS_NEED_BF16);

    hipMemsetAsync(wsmax, 0, 64, stream);
    maxabs_k<<<128, 256, 0, stream>>>(w, wsmax);
    quant_t_k5<<<WQ_N / 256, 256, 0, stream>>>(w, wsmax, wqt);
    halo_zero<<<514, 256, 0, stream>>>(xt3);
    pad_transpose<<<N_IMG * HWD, 256, 0, stream>>>(x, xt3);
    if (bf16path) {
        conv_m<true><<<1568, 256, 0, stream>>>(xt3, wqt, out, cvout, P);
        stats_fin<<<K_OUT, 256, 0, stream>>>(P, gamma, beta, stats);
        bn_relu_nchw<<<K_OUT * 49, 256, 0, stream>>>(cvout, out, stats);
    } else {
        conv_m<false><<<1568, 256, 0, stream>>>(xt3, wqt, out, cvout, P);
        stats_fin<<<K_OUT, 256, 0, stream>>>(P, gamma, beta, stats);
        bn_relu_f32<<<4096, 256, 0, stream>>>(out, stats);
    }
}

// Round 16
// 130.970 us; speedup vs baseline: 1.1619x; 1.0017x over previous
//
#include <hip/hip_runtime.h>

typedef unsigned short u16;
typedef unsigned int u32;
typedef __attribute__((ext_vector_type(4))) float f32x4;
typedef __attribute__((ext_vector_type(8))) short short8;

#define HWD 56
#define HW2 3136
#define C_IN 128
#define K_OUT 256
#define N_IMG 32
#define CHW_IN 401408
#define CHW_OUT 802816
#define PIX 100352
#define WQ_N 294912
// xt3: [cq4][gRow 1872][58][c32] bf16. Image n = gRows n*58 .. n*58+57 (rows n*58, n*58+57 zero).
#define GROWS 1872
#define XROW 1856
#define XPLANE (GROWS * XROW)
#define NSLICE 1568            // 784 nt * 2 wn
#define CV_OFF 33554432u
#define WS_NEED_BF16 (CV_OFF + (size_t)PIX * K_OUT * 2)

__device__ __forceinline__ u16 f2bf(float f) {
    u32 u = __float_as_uint(f);
    u32 r = u + 0x7FFFu + ((u >> 16) & 1u);
    return (u16)(r >> 16);
}

__device__ __forceinline__ void glds16(const u16* g, u16* l) {
    __builtin_amdgcn_global_load_lds(
        (const __attribute__((address_space(1))) void*)g,
        (__attribute__((address_space(3))) void*)l, 16, 0, 0);
}

__global__ void maxabs_k(const float* __restrict__ w, u32* __restrict__ wsmax) {
    float m = 0.f;
    for (int i = blockIdx.x * blockDim.x + threadIdx.x; i < WQ_N; i += gridDim.x * blockDim.x)
        m = fmaxf(m, fabsf(w[i]));
    for (int off = 32; off; off >>= 1)
        m = fmaxf(m, __shfl_xor(m, off));
    __shared__ float sm[4];
    int lane = threadIdx.x & 63, wid = threadIdx.x >> 6;
    if (lane == 0) sm[wid] = m;
    __syncthreads();
    if (threadIdx.x == 0) {
        float mm = fmaxf(fmaxf(sm[0], sm[1]), fmaxf(sm[2], sm[3]));
        atomicMax(wsmax, __float_as_uint(mm));
    }
}

// wqt: [kt36][mt2][oct4][m128][8]; kt = cq*9 + tap; c = cq*32 + oct*8 + j; m = mt*128 + mrow
__global__ void quant_t_k5(const float* __restrict__ w, const u32* __restrict__ wsmax,
                           u16* __restrict__ wqt) {
    int o = blockIdx.x * 256 + threadIdx.x;
    if (o >= WQ_N) return;
    int j = o & 7;
    int mrow = (o >> 3) & 127;
    int oct = (o >> 10) & 3;
    int mt = (o >> 12) & 1;
    int kt = o >> 13;
    int cq = kt / 9, tap = kt - cq * 9;
    int c = cq * 32 + oct * 8 + j;
    int m = mt * 128 + mrow;
    float scale = __uint_as_float(wsmax[0]) / 7.0f;
    float q = rintf(w[(m * 128 + c) * 9 + tap] / scale);
    q = fminf(fmaxf(q, -7.0f), 7.0f);
    wqt[o] = f2bf(q * scale);
}

// zero halos of xt3: full rows {n*58, n*58+57, 1856..1871} + data-row cols {0,57}
__global__ void halo_zero(u16* __restrict__ xt3) {
    int i = blockIdx.x * 256 + threadIdx.x;   // 131,584 total
    u32 addr;
    if (i < 74240) {
        int rowIdx = i / 928, rem = i - rowIdx * 928;
        int cq = rem / 232, c = rem - cq * 232;
        int row = rowIdx < 64 ? (rowIdx >> 1) * 58 + (rowIdx & 1) * 57 : 1856 + (rowIdx - 64);
        addr = (u32)cq * XPLANE + row * XROW + c * 8;
    } else {
        int j = i - 74240;
        int rowd = j >> 5, rem = j & 31;
        int side = rem >> 4, cq = (rem >> 2) & 3, o4 = rem & 3;
        int n = rowd / 56, h = rowd - n * 56;
        int row = n * 58 + 1 + h, col = side * 57;
        addr = (u32)cq * XPLANE + (row * 58 + col) * 32 + o4 * 8;
    }
    *(uint4*)(xt3 + addr) = (uint4){0, 0, 0, 0};
}

// x (NCHW f32) -> xt3 interior
__global__ __launch_bounds__(256) void pad_transpose(const float* __restrict__ x,
                                                     u16* __restrict__ xt3) {
    __shared__ float T[128][57];
    const int tid = threadIdx.x;
    const int n = blockIdx.x / HWD;
    const int h = blockIdx.x - n * HWD;
    const float* srow = x + (size_t)n * CHW_IN + h * HWD;
    #pragma unroll
    for (int it = 0; it < 7; ++it) {
        int i = tid + it * 256;
        int c = i / 14, q = i - c * 14;
        float4 v = *(const float4*)(srow + c * HW2 + q * 4);
        T[c][q * 4 + 0] = v.x; T[c][q * 4 + 1] = v.y;
        T[c][q * 4 + 2] = v.z; T[c][q * 4 + 3] = v.w;
    }
    __syncthreads();
    const int gRow = n * 58 + 1 + h;
    #pragma unroll
    for (int it = 0; it < 4; ++it) {
        int i = tid + it * 256;
        if (i < 56 * 16) {
            int w = i >> 4, oc = i & 15;
            int cq = oc >> 2, o4 = oc & 3;
            union { u16 us[8]; uint4 v4; } pk;
            #pragma unroll
            for (int j = 0; j < 8; ++j) pk.us[j] = f2bf(T[oc * 8 + j][w]);
            *(uint4*)(xt3 + (size_t)cq * XPLANE + (gRow * 58 + (w + 1)) * 32 + o4 * 8) = pk.v4;
        }
    }
}

// ===== R13 + compiler-scheduled LDS reads (no forced lgkmcnt(0) drain before MFMA) =====
// Block 128ch(mt) x 128px, 4 waves (2wm x 2wn, 64x64 each). 3-buf BK=32 counted-vmcnt.
// Grid 1568: mt-pairs adjacent on same XCD run CONCURRENTLY and share B in L2 (load-bearing).
// B glds: lane -> (oct=lane>>4, px=lane&15): 1 KB contiguous span per instruction.
// LDS B layout [pg8][oct4][px16][8]: frag read 256B-contiguous per quarter-wave, conflict-free.
template <bool BF16OUT>
__global__ __launch_bounds__(256, 3) void conv_m(const u16* __restrict__ xt3,
                                                 const u16* __restrict__ wqt,
                                                 float* __restrict__ out,
                                                 u16* __restrict__ cvout,
                                                 float* __restrict__ P) {
    __shared__ __align__(16) u16 lds[3][2][4096];   // 48 KB
    const int tid = threadIdx.x;
    const int lane = tid & 63;
    const int w4 = tid >> 6;           // 4 waves, 2m x 2n
    const int wm = w4 >> 1, wn = w4 & 1;
    const int fr = lane & 15, fq = lane >> 4;
    // XCD swizzle: 1568 = 8*196 bijective; mt-pairs (same nt) adjacent on same XCD
    const int swz = (blockIdx.x & 7) * 196 + (blockIdx.x >> 3);
    const int nt = swz >> 1, mt = swz & 1;
    const int pixbase = nt * 128;

    // dense-B per-lane sites: instr j covers px group pg = w4*2+j (16 px), this lane's
    // px = pg*16 + (lane&15), oct = lane>>4. Site = elem offset in cq plane at tap (0,0).
    u32 siteJ[2];
    #pragma unroll
    for (int j = 0; j < 2; ++j) {
        int px = pixbase + (w4 * 2 + j) * 16 + (lane & 15);
        int img = px / HW2, hw = px - img * HW2;
        int g = img * 58 + 1 + hw / HWD;
        int wc = hw % HWD + 1;
        siteJ[j] = (u32)(((g - 1) * 58 + (wc - 1)) * 32 + (lane >> 4) * 8);
    }

#define STAGE(buf, kt_) do {                                                     \
        const int cq_ = (kt_) / 9, tap_ = (kt_) % 9;                             \
        const int r_ = tap_ / 3, s_ = tap_ - r_ * 3;                             \
        const u16* ga_ = wqt + (size_t)((kt_) * 2 + mt) * 4096 + (w4 * 2) * 512 + lane * 8; \
        glds16(ga_,       &lds[buf][0][(w4 * 2 + 0) * 512]);                     \
        glds16(ga_ + 512, &lds[buf][0][(w4 * 2 + 1) * 512]);                     \
        const u16* gb_ = xt3 + (size_t)cq_ * XPLANE + (r_ * 58 + s_) * 32;       \
        glds16(gb_ + siteJ[0], &lds[buf][1][(w4 * 2 + 0) * 512]);                \
        glds16(gb_ + siteJ[1], &lds[buf][1][(w4 * 2 + 1) * 512]);                \
    } while (0)
// NOTE (R16): no lgkmcnt(0)/sched_barrier before the MFMA cluster — the compiler
// emits fine-grained lgkmcnt between ds_read and dependent MFMA (m97), interleaving
// reads with MFMAs instead of serially exposing the full LDS-read latency per phase.
// Correctness: reads of buf t cannot hoist above GATE(t-1)'s asm "memory" clobber.
#define PHASE_BODY(buf) do {                                                     \
        short8 af[4], bf[4];                                                     \
        _Pragma("unroll") for (int mi = 0; mi < 4; ++mi)                         \
            af[mi] = *(const short8*)&lds[buf][0][fq * 1024 + (wm * 64 + mi * 16 + fr) * 8]; \
        _Pragma("unroll") for (int ni = 0; ni < 4; ++ni)                         \
            bf[ni] = *(const short8*)&lds[buf][1][(wn * 4 + ni) * 512 + fq * 128 + fr * 8]; \
        __builtin_amdgcn_s_setprio(1);                                           \
        _Pragma("unroll") for (int mi = 0; mi < 4; ++mi)                         \
            _Pragma("unroll") for (int ni = 0; ni < 4; ++ni)                     \
                acc[mi][ni] = __builtin_amdgcn_mfma_f32_16x16x32_bf16(           \
                    af[mi], bf[ni], acc[mi][ni], 0, 0, 0);                       \
        __builtin_amdgcn_s_setprio(0);                                           \
    } while (0)
#define BAR() __builtin_amdgcn_s_barrier()
#define GATE4() asm volatile("s_waitcnt vmcnt(4)" ::: "memory")
#define GATE0() asm volatile("s_waitcnt vmcnt(0)" ::: "memory")

    f32x4 acc[4][4];
    #pragma unroll
    for (int a = 0; a < 4; ++a)
        #pragma unroll
        for (int b = 0; b < 4; ++b)
            acc[a][b] = (f32x4){0.f, 0.f, 0.f, 0.f};

    // prologue: kt0 -> buf0, kt1 -> buf1; keep kt1's 4 in flight
    STAGE(0, 0);
    STAGE(1, 1);
    GATE4();
    BAR();

    #pragma unroll 1
    for (int tt = 0; tt < 12; ++tt) {
        #pragma unroll
        for (int u = 0; u < 3; ++u) {
            const int t = tt * 3 + u;
            const int bs = (u + 2) % 3;
            if (t < 34) STAGE(bs, t + 2);
            PHASE_BODY(u);
            if (t < 34) GATE4();
            else if (t == 34) GATE0();
            BAR();
        }
    }
#undef STAGE
#undef PHASE_BODY

    // ---- fused per-channel partials (D: col=lane&15 -> pixel, row -> channel) ----
    const int slice = nt * 2 + wn;
    #pragma unroll
    for (int mi = 0; mi < 4; ++mi)
        #pragma unroll
        for (int j = 0; j < 4; ++j) {
            float s = 0.f, q = 0.f;
            #pragma unroll
            for (int ni = 0; ni < 4; ++ni) {
                float v = acc[mi][ni][j];
                s += v; q += v * v;
            }
            #pragma unroll
            for (int msk = 1; msk < 16; msk <<= 1) {
                s += __shfl_xor(s, msk);
                q += __shfl_xor(q, msk);
            }
            if (fr == 0) {
                int ch = mt * 128 + wm * 64 + mi * 16 + fq * 4 + j;
                float* dst = P + ((size_t)ch * NSLICE + slice) * 2;
                dst[0] = s; dst[1] = q;
            }
        }

    if (BF16OUT) {
        // dense epilogue: LDS transpose to T[ch128][px 136pad], 16B stores
        u16* T = (u16*)&lds[0][0][0];        // 34,816 B of the 48KB
        #pragma unroll
        for (int mi = 0; mi < 4; ++mi)
            #pragma unroll
            for (int ni = 0; ni < 4; ++ni) {
                int px_l = wn * 64 + ni * 16 + fr;
                int ch_l = wm * 64 + mi * 16 + fq * 4;
                #pragma unroll
                for (int j = 0; j < 4; ++j)
                    T[(ch_l + j) * 136 + px_l] = f2bf(acc[mi][ni][j]);
            }
        __syncthreads();
        #pragma unroll
        for (int it = 0; it < 8; ++it) {
            int q = tid + it * 256;
            int ch_l = q >> 4, pg = q & 15;
            uint4 v = *(const uint4*)&T[ch_l * 136 + pg * 8];
            *(uint4*)&cvout[(size_t)(mt * 128 + ch_l) * PIX + pixbase + pg * 8] = v;
        }
    } else {
        #pragma unroll
        for (int ni = 0; ni < 4; ++ni) {
            int pix = pixbase + wn * 64 + ni * 16 + fr;
            int n = pix / HW2;
            int hw = pix - n * HW2;
            size_t obase = (size_t)n * CHW_OUT + hw;
            #pragma unroll
            for (int mi = 0; mi < 4; ++mi) {
                int ch = mt * 128 + wm * 64 + mi * 16 + fq * 4;
                #pragma unroll
                for (int j = 0; j < 4; ++j)
                    out[obase + (size_t)(ch + j) * HW2] = acc[mi][ni][j];
            }
        }
    }
#undef BAR
#undef GATE4
#undef GATE0
}

__global__ void stats_fin(const float* __restrict__ P, const float* __restrict__ gamma,
                          const float* __restrict__ beta, float* __restrict__ stats) {
    int ch = blockIdx.x;
    int tid = threadIdx.x;
    float s = 0.f, q = 0.f;
    const float* base = P + (size_t)ch * NSLICE * 2;
    for (int i = tid; i < NSLICE; i += 256) {
        float2 v = *(const float2*)(base + i * 2);
        s += v.x; q += v.y;
    }
    for (int m = 32; m; m >>= 1) { s += __shfl_xor(s, m); q += __shfl_xor(q, m); }
    __shared__ float ss[4], qs[4];
    int l = tid & 63, w = tid >> 6;
    if (l == 0) { ss[w] = s; qs[w] = q; }
    __syncthreads();
    if (tid == 0) {
        float S = ss[0] + ss[1] + ss[2] + ss[3];
        float Q = qs[0] + qs[1] + qs[2] + qs[3];
        float mean = S / (float)PIX;
        float var = Q / (float)PIX - mean * mean;
        float inv = gamma[ch] * rsqrtf(var + 1e-5f);
        stats[2 * ch] = inv;
        stats[2 * ch + 1] = beta[ch] - mean * inv;
    }
}

// cvout [ch][global-pix] bf16 -> out NCHW f32
__global__ void bn_relu_nchw(const u16* __restrict__ cvout, float* __restrict__ out,
                             const float* __restrict__ stats) {
    const int b = blockIdx.x;            // 256 ch * 49 groups
    const int ch = b / 49, g = b - ch * 49;
    const float inv = stats[2 * ch], sh = stats[2 * ch + 1];
    const int p8 = (g * 256 + threadIdx.x) * 8;
    short8 v = *(const short8*)&cvout[(size_t)ch * PIX + p8];
    const int n = p8 / HW2;
    const int hw = p8 - n * HW2;
    float* dst = out + ((size_t)n * K_OUT + ch) * HW2 + hw;
    f32x4 o0, o1;
    #pragma unroll
    for (int j = 0; j < 4; ++j) {
        float a = __uint_as_float(((u32)(u16)v[j]) << 16);
        float bb = __uint_as_float(((u32)(u16)v[j + 4]) << 16);
        o0[j] = fmaxf(a * inv + sh, 0.f);
        o1[j] = fmaxf(bb * inv + sh, 0.f);
    }
    *(f32x4*)dst = o0;
    *(f32x4*)(dst + 4) = o1;
}

__global__ void bn_relu_f32(float* __restrict__ out, const float* __restrict__ stats) {
    const int n4 = ((size_t)N_IMG * K_OUT * HW2) / 4;
    int stride = gridDim.x * blockDim.x;
    for (int i = blockIdx.x * blockDim.x + threadIdx.x; i < n4; i += stride) {
        int ch = (i / (HW2 / 4)) & (K_OUT - 1);
        float inv = stats[2 * ch], sh = stats[2 * ch + 1];
        f32x4 v = ((f32x4*)out)[i];
        #pragma unroll
        for (int j = 0; j < 4; ++j)
            v[j] = fmaxf(v[j] * inv + sh, 0.f);
        ((f32x4*)out)[i] = v;
    }
}

extern "C" void kernel_launch(void* const* d_in, const int* in_sizes, int n_in,
                              void* d_out, int out_size, void* d_ws, size_t ws_size,
                              hipStream_t stream) {
    const float* x = (const float*)d_in[0];
    const float* w = (const float*)d_in[1];
    const float* gamma = (const float*)d_in[2];
    const float* beta = (const float*)d_in[3];
    float* out = (float*)d_out;

    char* ws = (char*)d_ws;
    u32* wsmax = (u32*)ws;                         // [0,64)
    float* stats = (float*)(ws + 64);              // 2KB
    u16* wqt = (u16*)(ws + 4096);                  // 589,824 B
    float* P = (float*)(ws + 1048576u);            // 3,211,264 B
    u16* xt3 = (u16*)(ws + 4325376u);              // 27,795,456 B (ends 32,120,832)
    u16* cvout = (u16*)(ws + CV_OFF);              // 51,380,224 B
    const bool bf16path = (ws_size >= WS_NEED_BF16);

    hipMemsetAsync(wsmax, 0, 64, stream);
    maxabs_k<<<128, 256, 0, stream>>>(w, wsmax);
    quant_t_k5<<<WQ_N / 256, 256, 0, stream>>>(w, wsmax, wqt);
    halo_zero<<<514, 256, 0, stream>>>(xt3);
    pad_transpose<<<N_IMG * HWD, 256, 0, stream>>>(x, xt3);
    if (bf16path) {
        conv_m<true><<<1568, 256, 0, stream>>>(xt3, wqt, out, cvout, P);
        stats_fin<<<K_OUT, 256, 0, stream>>>(P, gamma, beta, stats);
        bn_relu_nchw<<<K_OUT * 49, 256, 0, stream>>>(cvout, out, stats);
    } else {
        conv_m<false><<<1568, 256, 0, stream>>>(xt3, wqt, out, cvout, P);
        stats_fin<<<K_OUT, 256, 0, stream>>>(P, gamma, beta, stats);
        bn_relu_f32<<<4096, 256, 0, stream>>>(out, stats);
    }
}